// Round 4
// baseline (269.014 us; speedup 1.0000x reference)
//
#include <hip/hip_runtime.h>

#define T_TASKS 64
#define B_SEQS 262144

// cap_table[id][d] = 0.01 * CAP_MATRIX[d][id], id-major so a lane's 3 reads
// are consecutive dwords; 13 ids * 3 -> 39 dwords, distinct ids hit distinct
// banks (3*id mod 32 all distinct for id in [0,13)), same-id lanes broadcast.
__constant__ float c_capT[13 * 3] = {
    0.01f *  0.0f, 0.01f *  0.0f, 0.01f *  0.0f,
    0.01f * 33.0f, 0.01f * 33.0f, 0.01f * 33.0f,
    0.01f * 50.0f, 0.01f * 49.0f, 0.01f * 42.0f,
    0.01f * 43.0f, 0.01f * 39.0f, 0.01f * 39.0f,
    0.01f * 56.0f, 0.01f * 58.0f, 0.01f * 44.0f,
    0.01f * 67.0f, 0.01f * 67.0f, 0.01f * 52.0f,
    0.01f * 62.0f, 0.01f * 60.0f, 0.01f * 49.0f,
    0.01f * 47.0f, 0.01f * 54.0f, 0.01f * 42.0f,
    0.01f * 50.0f, 0.01f * 52.0f, 0.01f * 45.0f,
    0.01f * 51.0f, 0.01f * 52.0f, 0.01f * 46.0f,
    0.01f * 64.0f, 0.01f * 67.0f, 0.01f * 52.0f,
    0.01f * 64.0f, 0.01f * 69.0f, 0.01f * 53.0f,
    0.01f * 68.0f, 0.01f * 71.0f, 0.01f * 56.0f,
};

__global__ __launch_bounds__(256) void trust_kernel(
    const int2* __restrict__ perf,    // (T, B) of int2 (perf0, perf1)
    const int*  __restrict__ obsids,  // (T, B)
    const int*  __restrict__ predids, // (B)
    const float* __restrict__ betas,  // (3)
    const float* __restrict__ zetas,  // (3)
    float* __restrict__ out)          // (B)
{
    __shared__ float s_cap[13 * 3];
    if (threadIdx.x < 13 * 3) s_cap[threadIdx.x] = c_capT[threadIdx.x];
    __syncthreads();

    const int b = blockIdx.x * blockDim.x + threadIdx.x;

    float c0 = 0.0f, c1 = 0.0f, c2 = 0.0f;
    const int2* pp = perf + b;
    const int*  op = obsids + b;

    #pragma unroll 8
    for (int t = 0; t < T_TASKS; ++t) {
        const int2 pf = pp[(size_t)t * B_SEQS];
        const int  id = op[(size_t)t * B_SEQS];
        const float o0 = s_cap[id * 3 + 0];
        const float o1 = s_cap[id * 3 + 1];
        const float o2 = s_cap[id * 3 + 2];
        const bool p0 = (pf.x != 0);
        const bool p1 = (pf.y != 0);
        const bool su = (!p0) && p1;   // success: max
        const bool fa = p0 && (!p1);   // failure: min
        c0 = su ? fmaxf(c0, o0) : (fa ? fminf(c0, o0) : c0);
        c1 = su ? fmaxf(c1, o1) : (fa ? fminf(c1, o1) : c1);
        c2 = su ? fmaxf(c2, o2) : (fa ? fminf(c2, o2) : c2);
    }

    const int pid = predids[b];
    const float r0 = s_cap[pid * 3 + 0];
    const float r1 = s_cap[pid * 3 + 1];
    const float r2 = s_cap[pid * 3 + 2];

    const float q0 = betas[0] * (r0 - c0);
    const float q1 = betas[1] * (r1 - c1);
    const float q2 = betas[2] * (r2 - c2);

    const float t0 = powf(1.0f + expf(q0), -zetas[0]);
    const float t1 = powf(1.0f + expf(q1), -zetas[1]);
    const float t2 = powf(1.0f + expf(q2), -zetas[2]);

    out[b] = t0 * t1 * t2;
}

extern "C" void kernel_launch(void* const* d_in, const int* in_sizes, int n_in,
                              void* d_out, int out_size, void* d_ws, size_t ws_size,
                              hipStream_t stream) {
    // d_in[0] = inptasksobs (unused by reference)
    const int2*  perf    = (const int2*)d_in[1];   // (T, B, 2) int32
    const int*   obsids  = (const int*)d_in[2];    // (T, B, 1) int32
    const int*   predids = (const int*)d_in[3];    // (B, 1) int32
    // d_in[4] = num_obs_tasks (unused by reference)
    const float* betas   = (const float*)d_in[5];  // (3,)
    const float* zetas   = (const float*)d_in[6];  // (3,)
    float* out = (float*)d_out;                    // (B, 1) float32

    const int threads = 256;
    const int blocks  = B_SEQS / threads;
    trust_kernel<<<blocks, threads, 0, stream>>>(perf, obsids, predids, betas, zetas, out);
}

// Round 5
// 268.663 us; speedup vs baseline: 1.0013x; 1.0013x over previous
//
#include <hip/hip_runtime.h>

#define T_TASKS 64
#define B_SEQS 262144
#define CHUNKS 4
#define OBS_PER_CHUNK 16      // T_TASKS / CHUNKS
#define SEQ_PER_BLOCK 64
#define BLOCK 256             // CHUNKS * SEQ_PER_BLOCK

#define POS_BIG  3.402823466e+38f
#define NEG_BIG -3.402823466e+38f

// cap_table[id][d] = 0.01 * CAP_MATRIX[d][id], id-major: lane's 3 reads are
// consecutive dwords; distinct ids -> distinct banks, same-id lanes broadcast.
__constant__ float c_capT[13 * 3] = {
    0.01f *  0.0f, 0.01f *  0.0f, 0.01f *  0.0f,
    0.01f * 33.0f, 0.01f * 33.0f, 0.01f * 33.0f,
    0.01f * 50.0f, 0.01f * 49.0f, 0.01f * 42.0f,
    0.01f * 43.0f, 0.01f * 39.0f, 0.01f * 39.0f,
    0.01f * 56.0f, 0.01f * 58.0f, 0.01f * 44.0f,
    0.01f * 67.0f, 0.01f * 67.0f, 0.01f * 52.0f,
    0.01f * 62.0f, 0.01f * 60.0f, 0.01f * 49.0f,
    0.01f * 47.0f, 0.01f * 54.0f, 0.01f * 42.0f,
    0.01f * 50.0f, 0.01f * 52.0f, 0.01f * 45.0f,
    0.01f * 51.0f, 0.01f * 52.0f, 0.01f * 46.0f,
    0.01f * 64.0f, 0.01f * 67.0f, 0.01f * 52.0f,
    0.01f * 64.0f, 0.01f * 69.0f, 0.01f * 53.0f,
    0.01f * 68.0f, 0.01f * 71.0f, 0.01f * 56.0f,
};

// The scan step is cap -> clamp-like: success = max(.,oc), failure = min(.,oc),
// else identity. All are x -> clamp(x,l,h), closed under composition:
//   apply max(.,a):  l = max(l,a), h = max(h,a)
//   apply min(.,a):  l = min(l,a), h = min(h,a)
//   compose later g after earlier f: l = clamp(lf,lg,hg), h = clamp(hf,lg,hg)
// Final cap = clamp(0, L, H). This makes the T-scan chunk-parallel.
__global__ __launch_bounds__(BLOCK) void trust_kernel(
    const int2* __restrict__ perf,    // (T, B) int2 (perf0, perf1)
    const int*  __restrict__ obsids,  // (T, B)
    const int*  __restrict__ predids, // (B)
    const float* __restrict__ betas,  // (3)
    const float* __restrict__ zetas,  // (3)
    float* __restrict__ out)          // (B)
{
    __shared__ float s_cap[13 * 3];
    __shared__ float s_lh[CHUNKS][SEQ_PER_BLOCK][6];
    if (threadIdx.x < 13 * 3) s_cap[threadIdx.x] = c_capT[threadIdx.x];
    __syncthreads();

    const int lane = threadIdx.x & (SEQ_PER_BLOCK - 1); // wave = one chunk of 64 seqs
    const int c    = threadIdx.x >> 6;                  // chunk index 0..3
    const int b    = blockIdx.x * SEQ_PER_BLOCK + lane;

    // ---- hoist all 32 loads into static-indexed register arrays (MLP) ----
    const size_t base = (size_t)(c * OBS_PER_CHUNK) * B_SEQS + (size_t)b;
    int2 pfa[OBS_PER_CHUNK];
    int  ida[OBS_PER_CHUNK];
    #pragma unroll
    for (int t = 0; t < OBS_PER_CHUNK; ++t) {
        pfa[t] = perf[base + (size_t)t * B_SEQS];
        ida[t] = obsids[base + (size_t)t * B_SEQS];
    }

    // ---- build this chunk's composed clamp (l,h) per dim ----
    float l0 = NEG_BIG, l1 = NEG_BIG, l2 = NEG_BIG;
    float h0 = POS_BIG, h1 = POS_BIG, h2 = POS_BIG;
    #pragma unroll
    for (int t = 0; t < OBS_PER_CHUNK; ++t) {
        const int   id = ida[t];
        const float o0 = s_cap[id * 3 + 0];
        const float o1 = s_cap[id * 3 + 1];
        const float o2 = s_cap[id * 3 + 2];
        const bool p0 = (pfa[t].x != 0);
        const bool p1 = (pfa[t].y != 0);
        const bool su = (!p0) && p1;   // success -> max(., oc)
        const bool fa = p0 && (!p1);   // failure -> min(., oc)
        l0 = su ? fmaxf(l0, o0) : (fa ? fminf(l0, o0) : l0);
        h0 = su ? fmaxf(h0, o0) : (fa ? fminf(h0, o0) : h0);
        l1 = su ? fmaxf(l1, o1) : (fa ? fminf(l1, o1) : l1);
        h1 = su ? fmaxf(h1, o1) : (fa ? fminf(h1, o1) : h1);
        l2 = su ? fmaxf(l2, o2) : (fa ? fminf(l2, o2) : l2);
        h2 = su ? fmaxf(h2, o2) : (fa ? fminf(h2, o2) : h2);
    }

    // stride-6 float writes: 2-way bank aliasing only (free on CDNA4)
    float* p = &s_lh[c][lane][0];
    p[0] = l0; p[1] = l1; p[2] = l2;
    p[3] = h0; p[4] = h1; p[5] = h2;
    __syncthreads();

    // ---- one thread per sequence combines the 4 chunks in time order ----
    if (threadIdx.x < SEQ_PER_BLOCK) {
        const int sl = threadIdx.x;
        float L0 = s_lh[0][sl][0], L1 = s_lh[0][sl][1], L2 = s_lh[0][sl][2];
        float H0 = s_lh[0][sl][3], H1 = s_lh[0][sl][4], H2 = s_lh[0][sl][5];
        #pragma unroll
        for (int cc = 1; cc < CHUNKS; ++cc) {
            const float lc0 = s_lh[cc][sl][0], lc1 = s_lh[cc][sl][1], lc2 = s_lh[cc][sl][2];
            const float hc0 = s_lh[cc][sl][3], hc1 = s_lh[cc][sl][4], hc2 = s_lh[cc][sl][5];
            L0 = fminf(fmaxf(L0, lc0), hc0);  H0 = fminf(fmaxf(H0, lc0), hc0);
            L1 = fminf(fmaxf(L1, lc1), hc1);  H1 = fminf(fmaxf(H1, lc1), hc1);
            L2 = fminf(fmaxf(L2, lc2), hc2);  H2 = fminf(fmaxf(H2, lc2), hc2);
        }
        const float c0 = fminf(fmaxf(0.0f, L0), H0);
        const float c1 = fminf(fmaxf(0.0f, L1), H1);
        const float c2 = fminf(fmaxf(0.0f, L2), H2);

        const int bb  = blockIdx.x * SEQ_PER_BLOCK + sl;
        const int pid = predids[bb];
        const float r0 = s_cap[pid * 3 + 0];
        const float r1 = s_cap[pid * 3 + 1];
        const float r2 = s_cap[pid * 3 + 2];

        const float q0 = betas[0] * (r0 - c0);
        const float q1 = betas[1] * (r1 - c1);
        const float q2 = betas[2] * (r2 - c2);

        const float t0 = powf(1.0f + expf(q0), -zetas[0]);
        const float t1 = powf(1.0f + expf(q1), -zetas[1]);
        const float t2 = powf(1.0f + expf(q2), -zetas[2]);

        out[bb] = t0 * t1 * t2;
    }
}

extern "C" void kernel_launch(void* const* d_in, const int* in_sizes, int n_in,
                              void* d_out, int out_size, void* d_ws, size_t ws_size,
                              hipStream_t stream) {
    // d_in[0] = inptasksobs (unused by reference)
    const int2*  perf    = (const int2*)d_in[1];   // (T, B, 2) int32
    const int*   obsids  = (const int*)d_in[2];    // (T, B, 1) int32
    const int*   predids = (const int*)d_in[3];    // (B, 1) int32
    // d_in[4] = num_obs_tasks (unused by reference)
    const float* betas   = (const float*)d_in[5];  // (3,)
    const float* zetas   = (const float*)d_in[6];  // (3,)
    float* out = (float*)d_out;                    // (B, 1) float32

    const int blocks = B_SEQS / SEQ_PER_BLOCK;     // 4096
    trust_kernel<<<blocks, BLOCK, 0, stream>>>(perf, obsids, predids, betas, zetas, out);
}

// Round 11
// 268.026 us; speedup vs baseline: 1.0037x; 1.0024x over previous
//
#include <hip/hip_runtime.h>

#define T_TASKS 64
#define B_SEQS 262144
#define BLOCK 256
#define HALF_T 32            // T_TASKS / 2, one t-half per thread
#define DEPTH 8              // prefetch ring depth (power of 2)

#define POS_BIG  3.402823466e+38f
#define NEG_BIG -3.402823466e+38f

// cap_table[id] = 0.01 * CAP_MATRIX[:,id], float4-padded so one ds_read_b128
// fetches all 3 dims. Distinct ids -> distinct bank groups, same-id broadcast.
__constant__ float c_capT[13][4] = {
    {0.00f, 0.00f, 0.00f, 0.f}, {0.33f, 0.33f, 0.33f, 0.f},
    {0.50f, 0.49f, 0.42f, 0.f}, {0.43f, 0.39f, 0.39f, 0.f},
    {0.56f, 0.58f, 0.44f, 0.f}, {0.67f, 0.67f, 0.52f, 0.f},
    {0.62f, 0.60f, 0.49f, 0.f}, {0.47f, 0.54f, 0.42f, 0.f},
    {0.50f, 0.52f, 0.45f, 0.f}, {0.51f, 0.52f, 0.46f, 0.f},
    {0.64f, 0.67f, 0.52f, 0.f}, {0.64f, 0.69f, 0.53f, 0.f},
    {0.68f, 0.71f, 0.56f, 0.f},
};

// scan step is clamp-composition (validated absmax=0 in R5):
//   success -> l=max(l,o), h=max(h,o); failure -> l=min(l,o), h=min(h,o)
//   apply chunk g after f: x = clamp(clamp(x, lf,hf), lg,hg)
// med3 identity: med3(x, s?o:-INF, f?o:+INF) == {max(x,o) | min(x,o) | x}
#define STEP(l, h, A, B)                          \
    l = __builtin_amdgcn_fmed3f(l, A, B);         \
    h = __builtin_amdgcn_fmed3f(h, A, B);

__global__ __launch_bounds__(BLOCK) void trust_kernel(
    const int4* __restrict__ perf2,   // (T, B/2) int4 = perf for seq pair
    const int2* __restrict__ obs2,    // (T, B/2) int2 = obsids for seq pair
    const int2* __restrict__ pred2,   // (B/2)    int2 = predids for seq pair
    const float* __restrict__ betas,  // (3)
    const float* __restrict__ zetas,  // (3)
    float2* __restrict__ out2)        // (B/2)
{
    __shared__ float4 s_cap[13];
    __shared__ float  s_lh[2][128][13];   // 12 used + 1 pad (stride 13 % 32)

    if (threadIdx.x < 13)
        s_cap[threadIdx.x] = *(const float4*)&c_capT[threadIdx.x][0];
    __syncthreads();

    const int tid = threadIdx.x;
    const int c   = tid >> 7;            // t-half: 0 -> t[0,32), 1 -> t[32,64)
    const int pr  = tid & 127;           // seq-pair slot in block
    const size_t pair      = (size_t)blockIdx.x * 128 + pr;
    const size_t rowStride = B_SEQS / 2;
    const size_t base      = (size_t)(c * HALF_T) * rowStride + pair;

    // ---- 8-deep prefetch ring: 16 vmem loads (12 KB/wave) in flight ----
    int4 pfa[DEPTH];
    int2 ida[DEPTH];
    #pragma unroll
    for (int i = 0; i < DEPTH; ++i) {
        pfa[i] = perf2[base + (size_t)i * rowStride];
        ida[i] = obs2 [base + (size_t)i * rowStride];
    }

    float la0=NEG_BIG, la1=NEG_BIG, la2=NEG_BIG;
    float ha0=POS_BIG, ha1=POS_BIG, ha2=POS_BIG;
    float lb0=NEG_BIG, lb1=NEG_BIG, lb2=NEG_BIG;
    float hb0=POS_BIG, hb1=POS_BIG, hb2=POS_BIG;

    #pragma unroll
    for (int t = 0; t < HALF_T; ++t) {
        const int  slot = t & (DEPTH - 1);     // compile-time (full unroll)
        const int4 pf = pfa[slot];
        const int2 id = ida[slot];
        if (t + DEPTH < HALF_T) {
            pfa[slot] = perf2[base + (size_t)(t + DEPTH) * rowStride];
            ida[slot] = obs2 [base + (size_t)(t + DEPTH) * rowStride];
        }
        const float4 oa = s_cap[id.x];
        const float4 ob = s_cap[id.y];
        const bool sa = (pf.x == 0) && (pf.y != 0);
        const bool fa = (pf.x != 0) && (pf.y == 0);
        const bool sb = (pf.z == 0) && (pf.w != 0);
        const bool fb = (pf.z != 0) && (pf.w == 0);

        const float Aa0 = sa ? oa.x : NEG_BIG, Ba0 = fa ? oa.x : POS_BIG;
        const float Aa1 = sa ? oa.y : NEG_BIG, Ba1 = fa ? oa.y : POS_BIG;
        const float Aa2 = sa ? oa.z : NEG_BIG, Ba2 = fa ? oa.z : POS_BIG;
        const float Ab0 = sb ? ob.x : NEG_BIG, Bb0 = fb ? ob.x : POS_BIG;
        const float Ab1 = sb ? ob.y : NEG_BIG, Bb1 = fb ? ob.y : POS_BIG;
        const float Ab2 = sb ? ob.z : NEG_BIG, Bb2 = fb ? ob.z : POS_BIG;

        STEP(la0, ha0, Aa0, Ba0)
        STEP(la1, ha1, Aa1, Ba1)
        STEP(la2, ha2, Aa2, Ba2)
        STEP(lb0, hb0, Ab0, Bb0)
        STEP(lb1, hb1, Ab1, Bb1)
        STEP(lb2, hb2, Ab2, Bb2)
    }

    float* dst = &s_lh[c][pr][0];
    dst[0]=la0; dst[1]=la1; dst[2]=la2; dst[3]=ha0; dst[4]=ha1; dst[5]=ha2;
    dst[6]=lb0; dst[7]=lb1; dst[8]=lb2; dst[9]=hb0; dst[10]=hb1; dst[11]=hb2;
    __syncthreads();

    // ---- one thread per pair: compose halves (t-order), clamp(0), logistic ----
    if (tid < 128) {
        const float* q0 = &s_lh[0][tid][0];   // earlier half
        const float* q1 = &s_lh[1][tid][0];   // later half

        float ca0 = fminf(fmaxf(0.0f, q0[0]), q0[3]);
        float ca1 = fminf(fmaxf(0.0f, q0[1]), q0[4]);
        float ca2 = fminf(fmaxf(0.0f, q0[2]), q0[5]);
        ca0 = fminf(fmaxf(ca0, q1[0]), q1[3]);
        ca1 = fminf(fmaxf(ca1, q1[1]), q1[4]);
        ca2 = fminf(fmaxf(ca2, q1[2]), q1[5]);

        float cb0 = fminf(fmaxf(0.0f, q0[6]), q0[9]);
        float cb1 = fminf(fmaxf(0.0f, q0[7]), q0[10]);
        float cb2 = fminf(fmaxf(0.0f, q0[8]), q0[11]);
        cb0 = fminf(fmaxf(cb0, q1[6]), q1[9]);
        cb1 = fminf(fmaxf(cb1, q1[7]), q1[10]);
        cb2 = fminf(fmaxf(cb2, q1[8]), q1[11]);

        const size_t pair = (size_t)blockIdx.x * 128 + tid;
        const int2 pid = pred2[pair];
        const float4 ra = s_cap[pid.x];
        const float4 rb = s_cap[pid.y];
        const float be0 = betas[0], be1 = betas[1], be2 = betas[2];
        const float ze0 = zetas[0], ze1 = zetas[1], ze2 = zetas[2];

        const float ta = powf(1.0f + expf(be0 * (ra.x - ca0)), -ze0)
                       * powf(1.0f + expf(be1 * (ra.y - ca1)), -ze1)
                       * powf(1.0f + expf(be2 * (ra.z - ca2)), -ze2);
        const float tb = powf(1.0f + expf(be0 * (rb.x - cb0)), -ze0)
                       * powf(1.0f + expf(be1 * (rb.y - cb1)), -ze1)
                       * powf(1.0f + expf(be2 * (rb.z - cb2)), -ze2);

        out2[pair] = make_float2(ta, tb);
    }
}

extern "C" void kernel_launch(void* const* d_in, const int* in_sizes, int n_in,
                              void* d_out, int out_size, void* d_ws, size_t ws_size,
                              hipStream_t stream) {
    // d_in[0] = inptasksobs (unused), d_in[4] = num_obs_tasks (unused)
    const int4*  perf2 = (const int4*)d_in[1];   // (T, B, 2) int32 as pair-int4
    const int2*  obs2  = (const int2*)d_in[2];   // (T, B, 1) int32 as pair-int2
    const int2*  pred2 = (const int2*)d_in[3];   // (B, 1) int32 as pair-int2
    const float* betas = (const float*)d_in[5];
    const float* zetas = (const float*)d_in[6];
    float2* out2 = (float2*)d_out;

    const int blocks = B_SEQS / 256;             // 256 seqs (128 pairs) per block
    trust_kernel<<<blocks, BLOCK, 0, stream>>>(perf2, obs2, pred2, betas, zetas, out2);
}